// Round 10
// baseline (182.384 us; speedup 1.0000x reference)
//
#include <hip/hip_runtime.h>
#include <math.h>

#define B_ 512
#define N_ 120

typedef __attribute__((ext_vector_type(8))) _Float16 f16x8;
typedef __attribute__((ext_vector_type(4))) _Float16 f16x4;
typedef __attribute__((ext_vector_type(2))) _Float16 f16x2;
typedef __attribute__((ext_vector_type(4))) float f32x4;
typedef __attribute__((ext_vector_type(2))) float f32x2;
typedef __attribute__((ext_vector_type(4))) int i32x4;

// DPP cross-lane add on the VALU pipe (no DS op). Trees are bitwise identical
// to shfl_xor butterflies: 0xB1=xor1, 0x4E=xor2; 0x141 (row_half_mirror) and
// 0x140 (row_mirror) are valid xor4/xor8 substitutes ONLY after the previous
// hops have made quads/8-halves uniform (fp add commutativity => bitwise same).
#define DPP_XOR1 0xB1
#define DPP_XOR2 0x4E
#define DPP_HMIR 0x141
#define DPP_MIR  0x140
template<int CTRL>
__device__ __forceinline__ float dpp_add(float v) {
    int x = __builtin_amdgcn_mov_dpp(__float_as_int(v), CTRL, 0xF, 0xF, true);
    return v + __int_as_float(x);
}

// --- explicit mixed-precision FMA: d = a * f16half(b) + c, exact f32 fma ---
__device__ __forceinline__ float mix_lo(float a, int b, float c) {
    float d;
    asm("v_fma_mix_f32 %0, %1, %2, %3 op_sel:[0,0,0] op_sel_hi:[0,1,0]"
        : "=v"(d) : "v"(a), "v"(b), "v"(c));
    return d;
}
__device__ __forceinline__ float mix_hi(float a, int b, float c) {
    float d;
    asm("v_fma_mix_f32 %0, %1, %2, %3 op_sel:[0,1,0] op_sel_hi:[0,1,0]"
        : "=v"(d) : "v"(a), "v"(b), "v"(c));
    return d;
}
// packed fp32 mul (gfx90a+)
__device__ __forceinline__ f32x2 pk_mul2(f32x2 a, f32x2 b) {
    f32x2 d;
    asm("v_pk_mul_f32 %0, %1, %2" : "=v"(d) : "v"(a), "v"(b));
    return d;
}
// pack two f32 -> two f16 (RTZ), result as raw i32 (builtin returns __fp16x2)
__device__ __forceinline__ int pkrtz_i32(float a, float b) {
    auto sp = __builtin_amdgcn_cvt_pkrtz(a, b);
    return *(int*)&sp;
}

// LDS union buffer offsets (f16 units):
//  phase A (setup..stage2): Wq 0 | Wk 4096 | Wv 8192 | T 12288 | xf 16384..24576
//  phase B (scan):          q_s 0 | k_s 7680 | v_s 15360 | o_f 23040..31232
//  persistent:              Wo 31232..35328
#define OFF_WQ 0
#define OFF_WK 4096
#define OFF_WV 8192
#define OFF_T  12288
#define OFF_XF 16384
#define OFF_QS 0
#define OFF_KS 7680
#define OFF_VS 15360
#define OFF_OF 23040
#define OFF_WO 31232
#define LDS_F16 35328

// 4 N-tiles of D = A(16x64) * W(64x64) via 16x16x32 f16 MFMA (2 k-steps each).
// wmat in B-frag order: vec-index = ntile*128 + kstep*64 + lane.
__device__ __forceinline__ void mm4(f16x8 a0, f16x8 a1, const _Float16* wmat,
                                    int lane, f32x4* acc) {
    const f16x8* wv = (const f16x8*)wmat;
    #pragma unroll
    for (int nt = 0; nt < 4; ++nt) {
        f32x4 z = {0.f, 0.f, 0.f, 0.f};
        z = __builtin_amdgcn_mfma_f32_16x16x32_f16(a0, wv[nt * 128 + lane], z, 0, 0, 0);
        z = __builtin_amdgcn_mfma_f32_16x16x32_f16(a1, wv[nt * 128 + 64 + lane], z, 0, 0, 0);
        acc[nt] = z;
    }
}

// A-frag f16 index for A[row][d]:
// (row>>4)*1024 + (d>>5)*512 + ((d>>3)&3)*128 + (row&15)*8 + (d&7)
__global__ __launch_bounds__(512, 4) void fused_kdn(
    const float* __restrict__ x, const float* __restrict__ g_norm,
    const float* __restrict__ Wq, const float* __restrict__ Wk,
    const float* __restrict__ Wv, const float* __restrict__ bv,
    const float* __restrict__ Wo, const float* __restrict__ bo,
    const float* __restrict__ g_post,
    const float* __restrict__ W1, const float* __restrict__ b1,
    const float* __restrict__ W2, const float* __restrict__ b2,
    float* out)
{
    __shared__ __align__(16) _Float16 L[LDS_F16];
    __shared__ __align__(16) float g_s[N_];  // gamma stays fp32 (decay bias compounds ^120)
    __shared__ float bv_s[64], bo_s[64];
    __shared__ float sW1[128], sb1[16], sW2[16], sb2_s[1];

    int tid = threadIdx.x, wave = tid >> 6, lane = tid & 63;
    int b = blockIdx.x;

    // ---------------- setup ----------------
    if (tid < 128) sW1[tid] = W1[tid];
    if (tid >= 128 && tid < 144) sb1[tid - 128] = b1[tid - 128];
    if (tid >= 144 && tid < 160) sW2[tid - 144] = W2[tid - 144];
    if (tid == 160) sb2_s[0] = b2[0];
    if (tid >= 192 && tid < 256) bv_s[tid - 192] = bv[tid - 192];
    if (tid >= 256 && tid < 320) bo_s[tid - 256] = bo[tid - 256];
    if (tid < 128) {   // zero A-frag tile 7 (pad rows 120..127) for xf and o_f
        f16x8 z = {0, 0, 0, 0, 0, 0, 0, 0};
        *(f16x8*)&L[OFF_XF + 7168 + tid * 8] = z;
        *(f16x8*)&L[OFF_OF + 7168 + tid * 8] = z;
    }
    int sn = tid & 63, sk0 = (tid >> 6) * 8;
    int widx = (sn >> 4) * 1024 + (sk0 >> 5) * 512 + ((((sk0 >> 3) & 3) << 4) + (sn & 15)) * 8;
    {
        const float* Ws[4] = { Wq, Wk, Wv, Wo };
        const int woff[4] = { OFF_WQ, OFF_WK, OFF_WV, OFF_WO };
        #pragma unroll
        for (int m = 0; m < 4; ++m) {
            f16x8 pv;
            #pragma unroll
            for (int j = 0; j < 8; ++j) pv[j] = (_Float16)Ws[m][(sk0 + j) * 64 + sn];
            *(f16x8*)&L[woff[m] + widx] = pv;
        }
        // DFT table: T[k][n] = n<32 ? cos(2pi k n/64) : sin(2pi k (n-32)/64)
        f16x8 pv;
        int nn = sn & 31;
        #pragma unroll
        for (int j = 0; j < 8; ++j) {
            int kk = ((sk0 + j) * nn) & 63;
            float a = (float)kk * (6.283185307179586f / 64.0f);
            float s, c; __sincosf(a, &s, &c);
            pv[j] = (_Float16)((sn < 32) ? c : s);
        }
        *(f16x8*)&L[OFF_T + widx] = pv;
    }
    __syncthreads();

    const float* xb = x + (size_t)b * N_ * 64;
    float* ob_g = out + (size_t)b * N_ * 64;

    // ---------------- stage 1: zc_rms(x) -> xf (A-frag fp16) ----------------
    {
        float gn = g_norm[lane];
        int hbase = (lane >> 5) * 512 + ((lane >> 3) & 3) * 128 + (lane & 7);
        #pragma unroll 5
        for (int c = 0; c < 15; ++c) {
            int row = wave * 15 + c;
            float xv = xb[row * 64 + lane];
            float sx = xv, sxx = xv * xv;
            sx = dpp_add<DPP_XOR1>(sx); sxx = dpp_add<DPP_XOR1>(sxx);
            sx = dpp_add<DPP_XOR2>(sx); sxx = dpp_add<DPP_XOR2>(sxx);
            sx = dpp_add<DPP_HMIR>(sx); sxx = dpp_add<DPP_HMIR>(sxx);
            sx = dpp_add<DPP_MIR >(sx); sxx = dpp_add<DPP_MIR >(sxx);
            sx += __shfl_xor(sx, 16);   sxx += __shfl_xor(sxx, 16);
            sx += __shfl_xor(sx, 32);   sxx += __shfl_xor(sxx, 32);
            float mean = sx * 0.015625f;
            float var  = sxx * 0.015625f - mean * mean;
            float h = (xv - mean) * rsqrtf(var + 1e-8f) * gn;
            float hp = __shfl_xor(h, 1);
            if (!(lane & 1)) {
                f16x2 pk2 = { (_Float16)h, (_Float16)hp };
                *(f16x2*)&L[OFF_XF + (row >> 4) * 1024 + (row & 15) * 8 + hbase] = pk2;
            }
        }
    }
    __syncthreads();

    // ---------------- stage 2: MFMA projections ----------------
    int grp = lane >> 4, li = lane & 15;
    int rbase = wave * 16 + grp * 4;
    {
        const f16x8* hfv = (const f16x8*)(L + OFF_XF);
        f16x8 a0 = hfv[wave * 128 + lane];
        f16x8 a1 = hfv[wave * 128 + 64 + lane];
        f32x4 accT[4];

        // gamma: |rfft| bins 0..31 (re: nt 0,1; im: nt 2,3), bands, MLP
        mm4(a0, a1, L + OFF_T, lane, accT);
        {
            int gb2 = lane & 48;
            #pragma unroll
            for (int reg = 0; reg < 4; ++reg) {
                float re1 = accT[0][reg], re2 = accT[1][reg];
                float im1 = accT[2][reg], im2 = accT[3][reg];
                float m1 = sqrtf(fmaf(re1, re1, im1 * im1));
                float m2 = sqrtf(fmaf(re2, re2, im2 * im2));
                m1 = dpp_add<DPP_XOR1>(m1); m2 = dpp_add<DPP_XOR1>(m2);
                m1 = dpp_add<DPP_XOR2>(m1); m2 = dpp_add<DPP_XOR2>(m2);
                float e1 = m1 * 0.25f, e2 = m2 * 0.25f;       // bands li>>2, 4+(li>>2)
                float tot = e1 + e2;
                tot = dpp_add<DPP_HMIR>(tot);   // xor4 (quads uniform after m-hops)
                tot = dpp_add<DPP_MIR >(tot);   // xor8
                float rinv = 1.0f / fmaxf(tot, 1e-8f);
                float en1 = e1 * rinv, en2 = e2 * rinv;
                float hs = sb1[li];
                #pragma unroll
                for (int i = 0; i < 4; ++i)
                    hs = fmaf(__shfl(en1, gb2 + (i << 2)), sW1[i * 16 + li], hs);
                #pragma unroll
                for (int i = 0; i < 4; ++i)
                    hs = fmaf(__shfl(en2, gb2 + (i << 2)), sW1[(i + 4) * 16 + li], hs);
                float act = hs / (1.0f + __expf(-hs));        // silu
                float p = act * sW2[li];
                p = dpp_add<DPP_XOR1>(p);
                p = dpp_add<DPP_XOR2>(p);
                p = dpp_add<DPP_HMIR>(p);
                p = dpp_add<DPP_MIR >(p);
                float raw = 1.0f / (1.0f + __expf(-(p + sb2_s[0])));
                int row = rbase + reg;
                if (li == 0 && row < N_) g_s[row] = fmaf(0.49f, raw, 0.5f);
            }
        }

        f32x4 accq[4], acck[4], accv[4];
        mm4(a0, a1, L + OFF_WQ, lane, accq);
        mm4(a0, a1, L + OFF_WK, lane, acck);
        mm4(a0, a1, L + OFF_WV, lane, accv);

        {
            f32x4 sq = accq[0]*accq[0] + accq[1]*accq[1] + accq[2]*accq[2] + accq[3]*accq[3];
            f32x4 sk = acck[0]*acck[0] + acck[1]*acck[1] + acck[2]*acck[2] + acck[3]*acck[3];
            #pragma unroll
            for (int reg = 0; reg < 4; ++reg) {
                float qs = sq[reg], ks = sk[reg];
                qs = dpp_add<DPP_XOR1>(qs); ks = dpp_add<DPP_XOR1>(ks);
                qs = dpp_add<DPP_XOR2>(qs); ks = dpp_add<DPP_XOR2>(ks);
                qs = dpp_add<DPP_HMIR>(qs); ks = dpp_add<DPP_HMIR>(ks);
                qs = dpp_add<DPP_MIR >(qs); ks = dpp_add<DPP_MIR >(ks);
                float rq = rsqrtf(qs + 1e-8f), rk = rsqrtf(ks + 1e-8f);
                #pragma unroll
                for (int nt = 0; nt < 4; ++nt) { accq[nt][reg] *= rq; acck[nt][reg] *= rk; }
            }
            #pragma unroll
            for (int nt = 0; nt < 4; ++nt) {
                float bvn = bv_s[nt * 16 + li];
                #pragma unroll
                for (int reg = 0; reg < 4; ++reg) accv[nt][reg] += bvn;
            }
        }
        __syncthreads();   // all waves done reading Wq/Wk/Wv/T/xf

        // writeback q/k/v as fp16, NATURAL column layout (R5-proven)
        #pragma unroll
        for (int reg = 0; reg < 4; ++reg) {
            int row = rbase + reg;
            if (row < N_) {
                int base = row * 64 + li;
                #pragma unroll
                for (int nt = 0; nt < 4; ++nt) {
                    L[OFF_QS + base + nt * 16] = (_Float16)accq[nt][reg];
                    L[OFF_KS + base + nt * 16] = (_Float16)acck[nt][reg];
                    L[OFF_VS + base + nt * 16] = (_Float16)accv[nt][reg];
                }
            }
        }
    }
    __syncthreads();

    // ---------------- stage 3: MFMA-scan (R9 structure), ABLATION: x2 -------
    // ABLATION ROUND: the rep<2 loop runs the ENTIRE scan twice with all
    // state (S2, ku, delta, gq) re-initialized inside; the second pass reads
    // the same unchanged q/k/v LDS and rewrites bit-identical o_f values.
    // Output is unchanged; dur_us - dur_R9 == scan wall time. Remove the
    // loop (rep<1) to restore the R9 kernel exactly.
    if (wave < 4) {
        int col = lane & 15;              // S local row owned; C col id; A row
        int kg  = lane >> 4;              // k-chunk group 0..3
        int c0  = kg * 8;                 // A/B k-chunk base
        int dd  = wave * 16 + col;        // GLOBAL d of this lane's S row
        int dpart = (dd >> 5) * 512 + ((dd >> 3) & 3) * 128 + (dd & 7);
        const _Float16* ksp  = L + OFF_KS;
        const _Float16* qsp  = L + OFF_QS;
        const _Float16* vown = L + OFF_VS + dd;   // v[t][dd]
        // A-operand source: row 0 (col==0) = q_t ; rows>=1 = k_{t+1}
        const _Float16* bbase = (col == 0) ? (qsp + c0) : (ksp + 64 + c0);
        const float fzero = 0.0f, fnegone = -1.0f;

        for (int rep = 0; rep < 2; ++rep) {
            f32x2 S2[8];
            #pragma unroll
            for (int j = 0; j < 8; ++j) { S2[j].x = 0.f; S2[j].y = 0.f; }

            // prologue: ku = k_0 ; delta_0 = clip(v_0 - 0)
            f16x8 ku0 = *(const f16x8*)&ksp[c0];
            f16x8 ku1 = *(const f16x8*)&ksp[c0 + 32];
            float delta;
            {
                int vv0 = (int)*(const unsigned short*)&vown[0];
                float mv = mix_lo(fnegone, vv0, fzero);                 // -v0
                float dneg = __builtin_amdgcn_fmed3f(mv, -5.f, 5.f);    // -clip(v0)
                delta = __int_as_float(__float_as_int(dneg) ^ 0x80000000);
            }
            float4 gq = *(const float4*)&g_s[0];

#define UPD2(j, KW, DST)                                                       \
        {                                                                      \
            f32x2 t2 = pk_mul2(gt2, S2[j]);                                    \
            float sa = mix_lo(delta, KW, t2.x);                                \
            float sb = mix_hi(delta, KW, t2.y);                                \
            sa = __builtin_amdgcn_fmed3f(sa, -10.f, 10.f);                     \
            sb = __builtin_amdgcn_fmed3f(sb, -10.f, 10.f);                     \
            S2[j].x = sa; S2[j].y = sb;                                        \
            DST = pkrtz_i32(sa, sb);                                           \
        }

#define SCAN_IT(T, GT)                                                         \
        {                                                                      \
            f16x8 b0  = *(const f16x8*)&bbase[(T) * 64];                       \
            f16x8 b1  = *(const f16x8*)&bbase[(T) * 64 + 32];                  \
            f16x8 kn0 = *(const f16x8*)&ksp[((T) + 1) * 64 + c0];              \
            f16x8 kn1 = *(const f16x8*)&ksp[((T) + 1) * 64 + c0 + 32];         \
            int   vv  = (int)*(const unsigned short*)&vown[((T) + 1) * 64];    \
            float gt = (GT);                                                   \
            f32x2 gt2; gt2.x = gt; gt2.y = gt;                                 \
            i32x4 k0i = *(i32x4*)&ku0;                                         \
            i32x4 k1i = *(i32x4*)&ku1;                                         \
            i32x4 a0i, a1i;                                                    \
            UPD2(0, k0i[0], a0i[0]) UPD2(1, k0i[1], a0i[1])                    \
            UPD2(2, k0i[2], a0i[2]) UPD2(3, k0i[3], a0i[3])                    \
            UPD2(4, k1i[0], a1i[0]) UPD2(5, k1i[1], a1i[1])                    \
            UPD2(6, k1i[2], a1i[2]) UPD2(7, k1i[3], a1i[3])                    \
            f16x8 a0s = *(f16x8*)&a0i;                                         \
            f16x8 a1s = *(f16x8*)&a1i;                                         \
            float mv = mix_lo(fnegone, vv, fzero);                             \
            f32x4 Ca;                                                          \
            Ca[0] = (kg == 0) ? 0.f : mv;                                      \
            Ca[1] = mv; Ca[2] = mv; Ca[3] = mv;                                \
            Ca = __builtin_amdgcn_mfma_f32_16x16x32_f16(b0, a0s, Ca, 0, 0, 0); \
            f32x4 Cb = {0.f, 0.f, 0.f, 0.f};                                   \
            Cb = __builtin_amdgcn_mfma_f32_16x16x32_f16(b1, a1s, Cb, 0, 0, 0); \
            if (kg == 0)                                                       \
                L[OFF_OF + (((T) >> 4) * 1024) + (((T) & 15) * 8) + dpart] =   \
                    (_Float16)(Ca[0] + Cb[0]);                                 \
            float pa_ = (kg == 0) ? Ca[1] : Ca[0];                             \
            float pb_ = (kg == 0) ? Cb[1] : Cb[0];                             \
            float dneg = __builtin_amdgcn_fmed3f(pa_ + pb_, -5.f, 5.f);        \
            delta = __int_as_float(__float_as_int(dneg) ^ 0x80000000);         \
            ku0 = kn0; ku1 = kn1;                                              \
        }

            for (int t4 = 0; t4 < N_; t4 += 4) {
                float4 gq_n = (t4 + 4 < N_) ? *(const float4*)&g_s[t4 + 4] : gq;
                SCAN_IT(t4 + 0, gq.x)
                SCAN_IT(t4 + 1, gq.y)
                SCAN_IT(t4 + 2, gq.z)
                SCAN_IT(t4 + 3, gq.w)
                gq = gq_n;
            }
#undef SCAN_IT
#undef UPD2
        }
    }
    __syncthreads();

    // ---------------- stage 4a: zc_rms(o) in place in o_f (A-frag) ----------------
    {
        float gp = g_post[lane];
        int hbase = (lane >> 5) * 512 + ((lane >> 3) & 3) * 128 + (lane & 7);
        #pragma unroll 5
        for (int c = 0; c < 15; ++c) {
            int row = wave * 15 + c;
            int ridx = OFF_OF + (row >> 4) * 1024 + (row & 15) * 8;
            float ov = (float)L[ridx + hbase];
            float sx = ov, sxx = ov * ov;
            sx = dpp_add<DPP_XOR1>(sx); sxx = dpp_add<DPP_XOR1>(sxx);
            sx = dpp_add<DPP_XOR2>(sx); sxx = dpp_add<DPP_XOR2>(sxx);
            sx = dpp_add<DPP_HMIR>(sx); sxx = dpp_add<DPP_HMIR>(sxx);
            sx = dpp_add<DPP_MIR >(sx); sxx = dpp_add<DPP_MIR >(sxx);
            sx += __shfl_xor(sx, 16);   sxx += __shfl_xor(sxx, 16);
            sx += __shfl_xor(sx, 32);   sxx += __shfl_xor(sxx, 32);
            float mean = sx * 0.015625f;
            float var  = sxx * 0.015625f - mean * mean;
            float hn = (ov - mean) * rsqrtf(var + 1e-8f) * gp;
            float hp = __shfl_xor(hn, 1);
            if (!(lane & 1)) {
                f16x2 pk2 = { (_Float16)hn, (_Float16)hp };
                *(f16x2*)&L[ridx + hbase] = pk2;   // same-wave in-place, DS in-order
            }
        }
    }
    __syncthreads();

    // ---------------- stage 4b: out = x + zc_rms(o) @ Wo + bo ----------------
    {
        const f16x8* hfv = (const f16x8*)(L + OFF_OF);
        f16x8 a0 = hfv[wave * 128 + lane];
        f16x8 a1 = hfv[wave * 128 + 64 + lane];
        f32x4 acc[4];
        mm4(a0, a1, L + OFF_WO, lane, acc);
        #pragma unroll
        for (int reg = 0; reg < 4; ++reg) {
            int row = rbase + reg;
            if (row < N_) {
                #pragma unroll
                for (int nt = 0; nt < 4; ++nt) {
                    int idx = row * 64 + nt * 16 + li;
                    ob_g[idx] = acc[nt][reg] + bo_s[nt * 16 + li] + xb[idx];
                }
            }
        }
    }
}

extern "C" void kernel_launch(void* const* d_in, const int* in_sizes, int n_in,
                              void* d_out, int out_size, void* d_ws, size_t ws_size,
                              hipStream_t stream)
{
    const float* x      = (const float*)d_in[0];
    const float* g_norm = (const float*)d_in[1];
    const float* Wq     = (const float*)d_in[2];
    const float* Wk     = (const float*)d_in[3];
    const float* Wv     = (const float*)d_in[4];
    const float* bv     = (const float*)d_in[5];
    const float* Wo     = (const float*)d_in[6];
    const float* bo     = (const float*)d_in[7];
    const float* g_post = (const float*)d_in[8];
    const float* W1     = (const float*)d_in[9];
    const float* b1     = (const float*)d_in[10];
    const float* W2     = (const float*)d_in[11];
    const float* b2     = (const float*)d_in[12];
    float* out = (float*)d_out;

    fused_kdn<<<B_, 512, 0, stream>>>(x, g_norm, Wq, Wk, Wv, bv, Wo, bo, g_post,
                                      W1, b1, W2, b2, out);
}

// Round 11
// 145.112 us; speedup vs baseline: 1.2568x; 1.2568x over previous
//
#include <hip/hip_runtime.h>
#include <math.h>

#define B_ 512
#define N_ 120

typedef __attribute__((ext_vector_type(8))) _Float16 f16x8;
typedef __attribute__((ext_vector_type(4))) _Float16 f16x4;
typedef __attribute__((ext_vector_type(2))) _Float16 f16x2;
typedef __attribute__((ext_vector_type(4))) float f32x4;
typedef __attribute__((ext_vector_type(2))) float f32x2;
typedef __attribute__((ext_vector_type(4))) int i32x4;

// DPP cross-lane add on the VALU pipe (no DS op). Trees are bitwise identical
// to shfl_xor butterflies: 0xB1=xor1, 0x4E=xor2; 0x141 (row_half_mirror) and
// 0x140 (row_mirror) are valid xor4/xor8 substitutes ONLY after the previous
// hops have made quads/8-halves uniform (fp add commutativity => bitwise same).
#define DPP_XOR1 0xB1
#define DPP_XOR2 0x4E
#define DPP_HMIR 0x141
#define DPP_MIR  0x140
template<int CTRL>
__device__ __forceinline__ float dpp_add(float v) {
    int x = __builtin_amdgcn_mov_dpp(__float_as_int(v), CTRL, 0xF, 0xF, true);
    return v + __int_as_float(x);
}

// --- explicit mixed-precision FMA: d = a * f16half(b) + c, exact f32 fma ---
__device__ __forceinline__ float mix_lo(float a, int b, float c) {
    float d;
    asm("v_fma_mix_f32 %0, %1, %2, %3 op_sel:[0,0,0] op_sel_hi:[0,1,0]"
        : "=v"(d) : "v"(a), "v"(b), "v"(c));
    return d;
}
__device__ __forceinline__ float mix_hi(float a, int b, float c) {
    float d;
    asm("v_fma_mix_f32 %0, %1, %2, %3 op_sel:[0,1,0] op_sel_hi:[0,1,0]"
        : "=v"(d) : "v"(a), "v"(b), "v"(c));
    return d;
}
// negated-src0 variants: d = (-a) * f16half(b) + c  (exact sign flip)
__device__ __forceinline__ float mix_lo_n(float a, int b, float c) {
    float d;
    asm("v_fma_mix_f32 %0, -%1, %2, %3 op_sel:[0,0,0] op_sel_hi:[0,1,0]"
        : "=v"(d) : "v"(a), "v"(b), "v"(c));
    return d;
}
__device__ __forceinline__ float mix_hi_n(float a, int b, float c) {
    float d;
    asm("v_fma_mix_f32 %0, -%1, %2, %3 op_sel:[0,1,0] op_sel_hi:[0,1,0]"
        : "=v"(d) : "v"(a), "v"(b), "v"(c));
    return d;
}
// packed fp32 mul (gfx90a+)
__device__ __forceinline__ f32x2 pk_mul2(f32x2 a, f32x2 b) {
    f32x2 d;
    asm("v_pk_mul_f32 %0, %1, %2" : "=v"(d) : "v"(a), "v"(b));
    return d;
}
// pack two f32 -> two f16 (RTZ), result as raw i32 (builtin returns __fp16x2)
__device__ __forceinline__ int pkrtz_i32(float a, float b) {
    auto sp = __builtin_amdgcn_cvt_pkrtz(a, b);
    return *(int*)&sp;
}

// LDS union buffer offsets (f16 units):
//  phase A (setup..stage2): Wq 0 | Wk 4096 | Wv 8192 | T 12288 | xf 16384..24576
//  phase B (scan):          q_s 0 | k_s 7680 | v_s 15360 | o_f 23040..31232
//  persistent:              Wo 31232..35328
#define OFF_WQ 0
#define OFF_WK 4096
#define OFF_WV 8192
#define OFF_T  12288
#define OFF_XF 16384
#define OFF_QS 0
#define OFF_KS 7680
#define OFF_VS 15360
#define OFF_OF 23040
#define OFF_WO 31232
#define LDS_F16 35328

// 4 N-tiles of D = A(16x64) * W(64x64) via 16x16x32 f16 MFMA (2 k-steps each).
// wmat in B-frag order: vec-index = ntile*128 + kstep*64 + lane.
__device__ __forceinline__ void mm4(f16x8 a0, f16x8 a1, const _Float16* wmat,
                                    int lane, f32x4* acc) {
    const f16x8* wv = (const f16x8*)wmat;
    #pragma unroll
    for (int nt = 0; nt < 4; ++nt) {
        f32x4 z = {0.f, 0.f, 0.f, 0.f};
        z = __builtin_amdgcn_mfma_f32_16x16x32_f16(a0, wv[nt * 128 + lane], z, 0, 0, 0);
        z = __builtin_amdgcn_mfma_f32_16x16x32_f16(a1, wv[nt * 128 + 64 + lane], z, 0, 0, 0);
        acc[nt] = z;
    }
}

// A-frag f16 index for A[row][d]:
// (row>>4)*1024 + (d>>5)*512 + ((d>>3)&3)*128 + (row&15)*8 + (d&7)
__global__ __launch_bounds__(512, 4) void fused_kdn(
    const float* __restrict__ x, const float* __restrict__ g_norm,
    const float* __restrict__ Wq, const float* __restrict__ Wk,
    const float* __restrict__ Wv, const float* __restrict__ bv,
    const float* __restrict__ Wo, const float* __restrict__ bo,
    const float* __restrict__ g_post,
    const float* __restrict__ W1, const float* __restrict__ b1,
    const float* __restrict__ W2, const float* __restrict__ b2,
    float* out)
{
    __shared__ __align__(16) _Float16 L[LDS_F16];
    __shared__ __align__(16) float g_s[N_];  // gamma stays fp32 (decay bias compounds ^120)
    __shared__ float bv_s[64], bo_s[64];
    __shared__ float sW1[128], sb1[16], sW2[16], sb2_s[1];

    int tid = threadIdx.x, wave = tid >> 6, lane = tid & 63;
    int b = blockIdx.x;

    // ---------------- setup ----------------
    if (tid < 128) sW1[tid] = W1[tid];
    if (tid >= 128 && tid < 144) sb1[tid - 128] = b1[tid - 128];
    if (tid >= 144 && tid < 160) sW2[tid - 144] = W2[tid - 144];
    if (tid == 160) sb2_s[0] = b2[0];
    if (tid >= 192 && tid < 256) bv_s[tid - 192] = bv[tid - 192];
    if (tid >= 256 && tid < 320) bo_s[tid - 256] = bo[tid - 256];
    if (tid < 128) {   // zero A-frag tile 7 (pad rows 120..127) for xf and o_f
        f16x8 z = {0, 0, 0, 0, 0, 0, 0, 0};
        *(f16x8*)&L[OFF_XF + 7168 + tid * 8] = z;
        *(f16x8*)&L[OFF_OF + 7168 + tid * 8] = z;
    }
    int sn = tid & 63, sk0 = (tid >> 6) * 8;
    int widx = (sn >> 4) * 1024 + (sk0 >> 5) * 512 + ((((sk0 >> 3) & 3) << 4) + (sn & 15)) * 8;
    {
        const float* Ws[4] = { Wq, Wk, Wv, Wo };
        const int woff[4] = { OFF_WQ, OFF_WK, OFF_WV, OFF_WO };
        #pragma unroll
        for (int m = 0; m < 4; ++m) {
            f16x8 pv;
            #pragma unroll
            for (int j = 0; j < 8; ++j) pv[j] = (_Float16)Ws[m][(sk0 + j) * 64 + sn];
            *(f16x8*)&L[woff[m] + widx] = pv;
        }
        // DFT table: T[k][n] = n<32 ? cos(2pi k n/64) : sin(2pi k (n-32)/64)
        f16x8 pv;
        int nn = sn & 31;
        #pragma unroll
        for (int j = 0; j < 8; ++j) {
            int kk = ((sk0 + j) * nn) & 63;
            float a = (float)kk * (6.283185307179586f / 64.0f);
            float s, c; __sincosf(a, &s, &c);
            pv[j] = (_Float16)((sn < 32) ? c : s);
        }
        *(f16x8*)&L[OFF_T + widx] = pv;
    }
    __syncthreads();

    const float* xb = x + (size_t)b * N_ * 64;
    float* ob_g = out + (size_t)b * N_ * 64;

    // ---------------- stage 1: zc_rms(x) -> xf (A-frag fp16) ----------------
    {
        float gn = g_norm[lane];
        int hbase = (lane >> 5) * 512 + ((lane >> 3) & 3) * 128 + (lane & 7);
        #pragma unroll 5
        for (int c = 0; c < 15; ++c) {
            int row = wave * 15 + c;
            float xv = xb[row * 64 + lane];
            float sx = xv, sxx = xv * xv;
            sx = dpp_add<DPP_XOR1>(sx); sxx = dpp_add<DPP_XOR1>(sxx);
            sx = dpp_add<DPP_XOR2>(sx); sxx = dpp_add<DPP_XOR2>(sxx);
            sx = dpp_add<DPP_HMIR>(sx); sxx = dpp_add<DPP_HMIR>(sxx);
            sx = dpp_add<DPP_MIR >(sx); sxx = dpp_add<DPP_MIR >(sxx);
            sx += __shfl_xor(sx, 16);   sxx += __shfl_xor(sxx, 16);
            sx += __shfl_xor(sx, 32);   sxx += __shfl_xor(sxx, 32);
            float mean = sx * 0.015625f;
            float var  = sxx * 0.015625f - mean * mean;
            float h = (xv - mean) * rsqrtf(var + 1e-8f) * gn;
            float hp = __shfl_xor(h, 1);
            if (!(lane & 1)) {
                f16x2 pk2 = { (_Float16)h, (_Float16)hp };
                *(f16x2*)&L[OFF_XF + (row >> 4) * 1024 + (row & 15) * 8 + hbase] = pk2;
            }
        }
    }
    __syncthreads();

    // ---------------- stage 2: MFMA projections ----------------
    int grp = lane >> 4, li = lane & 15;
    int rbase = wave * 16 + grp * 4;
    {
        const f16x8* hfv = (const f16x8*)(L + OFF_XF);
        f16x8 a0 = hfv[wave * 128 + lane];
        f16x8 a1 = hfv[wave * 128 + 64 + lane];
        f32x4 accT[4];

        // gamma: |rfft| bins 0..31 (re: nt 0,1; im: nt 2,3), bands, MLP
        mm4(a0, a1, L + OFF_T, lane, accT);
        {
            int gb2 = lane & 48;
            #pragma unroll
            for (int reg = 0; reg < 4; ++reg) {
                float re1 = accT[0][reg], re2 = accT[1][reg];
                float im1 = accT[2][reg], im2 = accT[3][reg];
                float m1 = sqrtf(fmaf(re1, re1, im1 * im1));
                float m2 = sqrtf(fmaf(re2, re2, im2 * im2));
                m1 = dpp_add<DPP_XOR1>(m1); m2 = dpp_add<DPP_XOR1>(m2);
                m1 = dpp_add<DPP_XOR2>(m1); m2 = dpp_add<DPP_XOR2>(m2);
                float e1 = m1 * 0.25f, e2 = m2 * 0.25f;       // bands li>>2, 4+(li>>2)
                float tot = e1 + e2;
                tot = dpp_add<DPP_HMIR>(tot);   // xor4 (quads uniform after m-hops)
                tot = dpp_add<DPP_MIR >(tot);   // xor8
                float rinv = 1.0f / fmaxf(tot, 1e-8f);
                float en1 = e1 * rinv, en2 = e2 * rinv;
                float hs = sb1[li];
                #pragma unroll
                for (int i = 0; i < 4; ++i)
                    hs = fmaf(__shfl(en1, gb2 + (i << 2)), sW1[i * 16 + li], hs);
                #pragma unroll
                for (int i = 0; i < 4; ++i)
                    hs = fmaf(__shfl(en2, gb2 + (i << 2)), sW1[(i + 4) * 16 + li], hs);
                float act = hs / (1.0f + __expf(-hs));        // silu
                float p = act * sW2[li];
                p = dpp_add<DPP_XOR1>(p);
                p = dpp_add<DPP_XOR2>(p);
                p = dpp_add<DPP_HMIR>(p);
                p = dpp_add<DPP_MIR >(p);
                float raw = 1.0f / (1.0f + __expf(-(p + sb2_s[0])));
                int row = rbase + reg;
                if (li == 0 && row < N_) g_s[row] = fmaf(0.49f, raw, 0.5f);
            }
        }

        f32x4 accq[4], acck[4], accv[4];
        mm4(a0, a1, L + OFF_WQ, lane, accq);
        mm4(a0, a1, L + OFF_WK, lane, acck);
        mm4(a0, a1, L + OFF_WV, lane, accv);

        {
            f32x4 sq = accq[0]*accq[0] + accq[1]*accq[1] + accq[2]*accq[2] + accq[3]*accq[3];
            f32x4 sk = acck[0]*acck[0] + acck[1]*acck[1] + acck[2]*acck[2] + acck[3]*acck[3];
            #pragma unroll
            for (int reg = 0; reg < 4; ++reg) {
                float qs = sq[reg], ks = sk[reg];
                qs = dpp_add<DPP_XOR1>(qs); ks = dpp_add<DPP_XOR1>(ks);
                qs = dpp_add<DPP_XOR2>(qs); ks = dpp_add<DPP_XOR2>(ks);
                qs = dpp_add<DPP_HMIR>(qs); ks = dpp_add<DPP_HMIR>(ks);
                qs = dpp_add<DPP_MIR >(qs); ks = dpp_add<DPP_MIR >(ks);
                float rq = rsqrtf(qs + 1e-8f), rk = rsqrtf(ks + 1e-8f);
                #pragma unroll
                for (int nt = 0; nt < 4; ++nt) { accq[nt][reg] *= rq; acck[nt][reg] *= rk; }
            }
            #pragma unroll
            for (int nt = 0; nt < 4; ++nt) {
                float bvn = bv_s[nt * 16 + li];
                #pragma unroll
                for (int reg = 0; reg < 4; ++reg) accv[nt][reg] += bvn;
            }
        }
        __syncthreads();   // all waves done reading Wq/Wk/Wv/T/xf

        // writeback q/k/v as fp16, NATURAL column layout (R5-proven)
        #pragma unroll
        for (int reg = 0; reg < 4; ++reg) {
            int row = rbase + reg;
            if (row < N_) {
                int base = row * 64 + li;
                #pragma unroll
                for (int nt = 0; nt < 4; ++nt) {
                    L[OFF_QS + base + nt * 16] = (_Float16)accq[nt][reg];
                    L[OFF_KS + base + nt * 16] = (_Float16)acck[nt][reg];
                    L[OFF_VS + base + nt * 16] = (_Float16)accv[nt][reg];
                }
            }
        }
    }
    __syncthreads();

    // ---------------- stage 3: MFMA-scan, prefetched + neg-mod delta --------
    // R9 structure (fused o+pred MFMA pair, lane-local delta) with:
    //  * ONE-STEP REGISTER PREFETCH: all 5 LDS loads for step T+1 issue at the
    //    top of step T, before the delta-dependent UPD2 burst -> ds latency
    //    lands during T's MFMA wait, out of the serial chain (R10 ablation:
    //    scan = 40us of 71, ~800cy/step >> compute chain -> latency suspect).
    //  * dn carries -delta; sign folded into UPD2 via v_fma_mix -src0 modifier
    //    (exact) -> xor removed from chain.
    //  * s_setprio(1) around the critical UPD2->MFMA burst (waves are
    //    phase-independent across co-resident blocks).
    // Values bitwise identical to R9.
    if (wave < 4) {
        int col = lane & 15;              // S local row owned; C col id; A row
        int kg  = lane >> 4;              // k-chunk group 0..3
        int c0  = kg * 8;                 // A/B k-chunk base
        int dd  = wave * 16 + col;        // GLOBAL d of this lane's S row
        int dpart = (dd >> 5) * 512 + ((dd >> 3) & 3) * 128 + (dd & 7);
        const _Float16* ksp  = L + OFF_KS;
        const _Float16* qsp  = L + OFF_QS;
        const _Float16* vown = L + OFF_VS + dd;   // v[t][dd]
        // A-operand source: row 0 (col==0) = q_t ; rows>=1 = k_{t+1}
        const _Float16* bbase = (col == 0) ? (qsp + c0) : (ksp + 64 + c0);

        f32x2 S2[8];
        #pragma unroll
        for (int j = 0; j < 8; ++j) { S2[j].x = 0.f; S2[j].y = 0.f; }
        const float fzero = 0.0f, fnegone = -1.0f;

        // prologue: ku = k_0 ; prefetch step-0 operands ; dn = -clip(v_0)
        f16x8 ku0 = *(const f16x8*)&ksp[c0];
        f16x8 ku1 = *(const f16x8*)&ksp[c0 + 32];
        f16x8 pb0 = *(const f16x8*)&bbase[0];
        f16x8 pb1 = *(const f16x8*)&bbase[32];
        f16x8 pk0 = *(const f16x8*)&ksp[64 + c0];
        f16x8 pk1 = *(const f16x8*)&ksp[64 + c0 + 32];
        int   pvv = (int)*(const unsigned short*)&vown[64];
        float dn;
        {
            int vv0 = (int)*(const unsigned short*)&vown[0];
            float mv = mix_lo(fnegone, vv0, fzero);               // -v0
            dn = __builtin_amdgcn_fmed3f(mv, -5.f, 5.f);          // -clip(v0)
        }
        float4 gq = *(const float4*)&g_s[0];

#define UPD2(j, KW, DST)                                                       \
        {                                                                      \
            f32x2 t2 = pk_mul2(gt2, S2[j]);                                    \
            float sa = mix_lo_n(dn, KW, t2.x);                                 \
            float sb = mix_hi_n(dn, KW, t2.y);                                 \
            sa = __builtin_amdgcn_fmed3f(sa, -10.f, 10.f);                     \
            sb = __builtin_amdgcn_fmed3f(sb, -10.f, 10.f);                     \
            S2[j].x = sa; S2[j].y = sb;                                        \
            DST = pkrtz_i32(sa, sb);                                           \
        }

#define SCAN_IT(T, GT)                                                         \
        {                                                                      \
            f16x8 nb0 = *(const f16x8*)&bbase[((T) + 1) * 64];                 \
            f16x8 nb1 = *(const f16x8*)&bbase[((T) + 1) * 64 + 32];            \
            f16x8 nk0 = *(const f16x8*)&ksp[((T) + 2) * 64 + c0];              \
            f16x8 nk1 = *(const f16x8*)&ksp[((T) + 2) * 64 + c0 + 32];         \
            int   nvv = (int)*(const unsigned short*)&vown[((T) + 2) * 64];    \
            float gt = (GT);                                                   \
            f32x2 gt2; gt2.x = gt; gt2.y = gt;                                 \
            i32x4 k0i = *(i32x4*)&ku0;                                         \
            i32x4 k1i = *(i32x4*)&ku1;                                         \
            i32x4 a0i, a1i;                                                    \
            __builtin_amdgcn_s_setprio(1);                                     \
            UPD2(0, k0i[0], a0i[0]) UPD2(1, k0i[1], a0i[1])                    \
            UPD2(2, k0i[2], a0i[2]) UPD2(3, k0i[3], a0i[3])                    \
            UPD2(4, k1i[0], a1i[0]) UPD2(5, k1i[1], a1i[1])                    \
            UPD2(6, k1i[2], a1i[2]) UPD2(7, k1i[3], a1i[3])                    \
            f16x8 a0s = *(f16x8*)&a0i;                                         \
            f16x8 a1s = *(f16x8*)&a1i;                                         \
            float mv = mix_lo(fnegone, pvv, fzero);                            \
            f32x4 Ca;                                                          \
            Ca[0] = (kg == 0) ? 0.f : mv;                                      \
            Ca[1] = mv; Ca[2] = mv; Ca[3] = mv;                                \
            Ca = __builtin_amdgcn_mfma_f32_16x16x32_f16(pb0, a0s, Ca, 0, 0, 0);\
            f32x4 Cb = {0.f, 0.f, 0.f, 0.f};                                   \
            Cb = __builtin_amdgcn_mfma_f32_16x16x32_f16(pb1, a1s, Cb, 0, 0, 0);\
            __builtin_amdgcn_s_setprio(0);                                     \
            if (kg == 0)                                                       \
                L[OFF_OF + (((T) >> 4) * 1024) + (((T) & 15) * 8) + dpart] =   \
                    (_Float16)(Ca[0] + Cb[0]);                                 \
            float pa_ = (kg == 0) ? Ca[1] : Ca[0];                             \
            float pb_ = (kg == 0) ? Cb[1] : Cb[0];                             \
            dn = __builtin_amdgcn_fmed3f(pa_ + pb_, -5.f, 5.f);                \
            ku0 = pk0; ku1 = pk1;                                              \
            pb0 = nb0; pb1 = nb1; pk0 = nk0; pk1 = nk1; pvv = nvv;             \
        }

        for (int t4 = 0; t4 < N_; t4 += 4) {
            float4 gq_n = (t4 + 4 < N_) ? *(const float4*)&g_s[t4 + 4] : gq;
            SCAN_IT(t4 + 0, gq.x)
            SCAN_IT(t4 + 1, gq.y)
            SCAN_IT(t4 + 2, gq.z)
            SCAN_IT(t4 + 3, gq.w)
            gq = gq_n;
        }
#undef SCAN_IT
#undef UPD2
    }
    __syncthreads();

    // ---------------- stage 4a: zc_rms(o) in place in o_f (A-frag) ----------------
    {
        float gp = g_post[lane];
        int hbase = (lane >> 5) * 512 + ((lane >> 3) & 3) * 128 + (lane & 7);
        #pragma unroll 5
        for (int c = 0; c < 15; ++c) {
            int row = wave * 15 + c;
            int ridx = OFF_OF + (row >> 4) * 1024 + (row & 15) * 8;
            float ov = (float)L[ridx + hbase];
            float sx = ov, sxx = ov * ov;
            sx = dpp_add<DPP_XOR1>(sx); sxx = dpp_add<DPP_XOR1>(sxx);
            sx = dpp_add<DPP_XOR2>(sx); sxx = dpp_add<DPP_XOR2>(sxx);
            sx = dpp_add<DPP_HMIR>(sx); sxx = dpp_add<DPP_HMIR>(sxx);
            sx = dpp_add<DPP_MIR >(sx); sxx = dpp_add<DPP_MIR >(sxx);
            sx += __shfl_xor(sx, 16);   sxx += __shfl_xor(sxx, 16);
            sx += __shfl_xor(sx, 32);   sxx += __shfl_xor(sxx, 32);
            float mean = sx * 0.015625f;
            float var  = sxx * 0.015625f - mean * mean;
            float hn = (ov - mean) * rsqrtf(var + 1e-8f) * gp;
            float hp = __shfl_xor(hn, 1);
            if (!(lane & 1)) {
                f16x2 pk2 = { (_Float16)hn, (_Float16)hp };
                *(f16x2*)&L[ridx + hbase] = pk2;   // same-wave in-place, DS in-order
            }
        }
    }
    __syncthreads();

    // ---------------- stage 4b: out = x + zc_rms(o) @ Wo + bo ----------------
    {
        const f16x8* hfv = (const f16x8*)(L + OFF_OF);
        f16x8 a0 = hfv[wave * 128 + lane];
        f16x8 a1 = hfv[wave * 128 + 64 + lane];
        f32x4 acc[4];
        mm4(a0, a1, L + OFF_WO, lane, acc);
        #pragma unroll
        for (int reg = 0; reg < 4; ++reg) {
            int row = rbase + reg;
            if (row < N_) {
                #pragma unroll
                for (int nt = 0; nt < 4; ++nt) {
                    int idx = row * 64 + nt * 16 + li;
                    ob_g[idx] = acc[nt][reg] + bo_s[nt * 16 + li] + xb[idx];
                }
            }
        }
    }
}

extern "C" void kernel_launch(void* const* d_in, const int* in_sizes, int n_in,
                              void* d_out, int out_size, void* d_ws, size_t ws_size,
                              hipStream_t stream)
{
    const float* x      = (const float*)d_in[0];
    const float* g_norm = (const float*)d_in[1];
    const float* Wq     = (const float*)d_in[2];
    const float* Wk     = (const float*)d_in[3];
    const float* Wv     = (const float*)d_in[4];
    const float* bv     = (const float*)d_in[5];
    const float* Wo     = (const float*)d_in[6];
    const float* bo     = (const float*)d_in[7];
    const float* g_post = (const float*)d_in[8];
    const float* W1     = (const float*)d_in[9];
    const float* b1     = (const float*)d_in[10];
    const float* W2     = (const float*)d_in[11];
    const float* b2     = (const float*)d_in[12];
    float* out = (float*)d_out;

    fused_kdn<<<B_, 512, 0, stream>>>(x, g_norm, Wq, Wk, Wv, bv, Wo, bo, g_post,
                                      W1, b1, W2, b2, out);
}